// Round 11
// baseline (974.532 us; speedup 1.0000x reference)
//
#include <hip/hip_runtime.h>
#include <hip/hip_fp16.h>
#include <hip/hip_cooperative_groups.h>
#include <cstdint>
#include <cstddef>

namespace cg = cooperative_groups;

#define N_NODES 50000
#define N_EDGES 800000

typedef _Float16 f16x8 __attribute__((ext_vector_type(8)));
typedef float f32x4 __attribute__((ext_vector_type(4)));

// ---------------- cooperative graph-build + prep megakernel ----------------
// Phase A: zero cnt/bns, x->f16, W transposes | B: hist | C: scan | D: scatter(u16)
__launch_bounds__(256, 4)
__global__ void build_graph(const float* __restrict__ x, __half* __restrict__ xh,
                            int* __restrict__ cnt, float* __restrict__ bns,
                            const float* __restrict__ W0, const float* __restrict__ W1,
                            const float* __restrict__ W2, __half* __restrict__ t0,
                            __half* __restrict__ t1, __half* __restrict__ t2,
                            const float* __restrict__ pW1, const float* __restrict__ pW2,
                            __half* __restrict__ pt1, __half* __restrict__ pt2,
                            const int* __restrict__ es, const int* __restrict__ ed,
                            int* __restrict__ rs, int* __restrict__ cursor,
                            int* __restrict__ bsum, unsigned short* __restrict__ csr)
{
    cg::grid_group grid = cg::this_grid();
    __shared__ int sh[256];
    const int tid = threadIdx.x;
    const int gtid = blockIdx.x * 256 + tid;
    const int gsz = gridDim.x * 256;
    const int nchunks = (N_NODES + 255) / 256;   // 196

    // ---- Phase A ----
    for (int i = gtid; i < N_NODES; i += gsz) cnt[i] = 0;
    if (gtid < 512) bns[gtid] = 0.f;
    for (int i = gtid; i < N_NODES * 32; i += gsz) {
        float4 v = *reinterpret_cast<const float4*>(x + (size_t)i * 4);
        __half2 a = __floats2half2_rn(v.x, v.y);
        __half2 c = __floats2half2_rn(v.z, v.w);
        uint2 pk;
        pk.x = *reinterpret_cast<unsigned*>(&a);
        pk.y = *reinterpret_cast<unsigned*>(&c);
        *reinterpret_cast<uint2*>(xh + (size_t)i * 4) = pk;
    }
    for (int g = gtid; g < 40960; g += gsz) {
        if (g < 16384) {
            int c = g & 127, k = g >> 7;
            t0[(size_t)c * 128 + k] = __float2half(W0[(size_t)k * 128 + c]);
        } else if (g < 32768) {
            int idx = g - 16384;
            int c = idx & 127, k = idx >> 7;
            t1[(size_t)c * 128 + k] = __float2half(W1[(size_t)k * 128 + c]);
        } else {
            int idx = g - 32768;
            int c = idx & 63, k = idx >> 6;
            t2[(size_t)c * 128 + k] = __float2half(W2[(size_t)k * 64 + c]);
        }
    }
    for (int g = gtid; g < 8192; g += gsz) {
        if (g < 4096) {
            int c = g & 63, k = g >> 6;
            pt1[(size_t)c * 64 + k] = __float2half(pW1[(size_t)k * 64 + c]);
        } else {
            int idx = g - 4096;
            int c = idx & 63, k = idx >> 6;
            pt2[(size_t)c * 64 + k] = __float2half(pW2[(size_t)k * 64 + c]);
        }
    }
    grid.sync();

    // ---- Phase B: histogram ----
    for (int e = gtid; e < N_EDGES; e += gsz) atomicAdd(&cnt[ed[e]], 1);
    grid.sync();

    // ---- Phase C1: per-chunk totals ----
    for (int chunk = blockIdx.x; chunk < nchunks; chunk += gridDim.x) {
        int i = chunk * 256 + tid;
        int v = (i < N_NODES) ? cnt[i] : 0;
        sh[tid] = v;
        __syncthreads();
        for (int o = 128; o; o >>= 1) {
            if (tid < o) sh[tid] += sh[tid + o];
            __syncthreads();
        }
        if (tid == 0) bsum[chunk] = sh[0];
        __syncthreads();
    }
    grid.sync();

    // ---- Phase C2: block 0 exclusive-scans chunk totals ----
    if (blockIdx.x == 0) {
        int v = (tid < nchunks) ? bsum[tid] : 0;
        sh[tid] = v;
        __syncthreads();
        for (int o = 1; o < 256; o <<= 1) {
            int u = (tid >= o) ? sh[tid - o] : 0;
            __syncthreads();
            sh[tid] += u;
            __syncthreads();
        }
        if (tid < nchunks) bsum[tid] = tid ? sh[tid - 1] : 0;
    }
    grid.sync();

    // ---- Phase C3: finalize rs + cursor ----
    for (int chunk = blockIdx.x; chunk < nchunks; chunk += gridDim.x) {
        int i = chunk * 256 + tid;
        int v = (i < N_NODES) ? cnt[i] : 0;
        sh[tid] = v;
        __syncthreads();
        for (int o = 1; o < 256; o <<= 1) {
            int u = (tid >= o) ? sh[tid - o] : 0;
            __syncthreads();
            sh[tid] += u;
            __syncthreads();
        }
        int excl = sh[tid] - v + bsum[chunk];
        if (i < N_NODES) { rs[i] = excl; cursor[i] = excl; }
        if (i == N_NODES - 1) rs[N_NODES] = excl + v;
        __syncthreads();
    }
    grid.sync();

    // ---- Phase D: scatter (uint16 src ids) ----
    for (int e = gtid; e < N_EDGES; e += gsz) {
        int d = ed[e];
        int p = atomicAdd(&cursor[d], 1);
        csr[p] = (unsigned short)es[e];
    }
}

// ---------------- MFMA GEMM (n x 128) @ (128 x C) + optional fused BN+ReLU on input ----
template <int C, int H, bool BN>
__launch_bounds__(256, 3)
__global__ void gemm_mfma(const __half* __restrict__ Ah, const __half* __restrict__ Wt,
                          const float* __restrict__ al, const float* __restrict__ ar,
                          const float* __restrict__ bns, const float* __restrict__ bng,
                          const float* __restrict__ bnb,
                          __half* __restrict__ feat, float* __restrict__ el,
                          float* __restrict__ er, int n)
{
    constexpr int K = 128;
    constexpr int AS = 136;
    constexpr int CT = C / 16;
    __shared__ __half As[64 * AS];
    __shared__ __half Ws[C * AS];
    __shared__ float sc[128], sh_[128];

    const int tid = threadIdx.x;
    const int brow = blockIdx.x * 64;

    if constexpr (BN) {
        if (tid < 128) {
            const float invN = 1.f / (float)N_NODES;
            float mean = bns[tid] * invN;
            float var = bns[128 + tid] * invN - mean * mean;
            float s = bng[tid] * rsqrtf(var + 1e-5f);
            sc[tid] = s;
            sh_[tid] = bnb[tid] - mean * s;
        }
        __syncthreads();
    }

    for (int idx = tid; idx < 64 * 16; idx += 256) {
        int r = idx >> 4, u = idx & 15;
        int gr = brow + r;
        f16x8 v = {0, 0, 0, 0, 0, 0, 0, 0};
        if (gr < n) v = *reinterpret_cast<const f16x8*>(Ah + (size_t)gr * K + u * 8);
        if constexpr (BN) {
            #pragma unroll
            for (int e = 0; e < 8; ++e) {
                int ch = u * 8 + e;
                float f = (float)v[e] * sc[ch] + sh_[ch];
                v[e] = (_Float16)fmaxf(f, 0.f);
            }
        }
        *reinterpret_cast<f16x8*>(&As[r * AS + u * 8]) = v;
    }
    for (int idx = tid; idx < C * 16; idx += 256) {
        int c = idx >> 4, u = idx & 15;
        *reinterpret_cast<f16x8*>(&Ws[c * AS + u * 8]) =
            *reinterpret_cast<const f16x8*>(Wt + (size_t)c * K + u * 8);
    }
    __syncthreads();

    const int w = tid >> 6;
    const int l = tid & 63;
    const int l15 = l & 15;
    const int kg = l >> 4;

    f32x4 acc[CT];
    #pragma unroll
    for (int ct = 0; ct < CT; ++ct) acc[ct] = (f32x4){0.f, 0.f, 0.f, 0.f};

    #pragma unroll
    for (int kt = 0; kt < 4; ++kt) {
        f16x8 a = *reinterpret_cast<const f16x8*>(&As[(w * 16 + l15) * AS + kt * 32 + kg * 8]);
        #pragma unroll
        for (int ct = 0; ct < CT; ++ct) {
            f16x8 b = *reinterpret_cast<const f16x8*>(&Ws[(ct * 16 + l15) * AS + kt * 32 + kg * 8]);
            acc[ct] = __builtin_amdgcn_mfma_f32_16x16x32_f16(a, b, acc[ct], 0, 0, 0);
        }
    }

    const int row0 = w * 16 + kg * 4;
    float pel[4][H], per_[4][H];
    #pragma unroll
    for (int j = 0; j < 4; ++j)
        #pragma unroll
        for (int h = 0; h < H; ++h) { pel[j][h] = 0.f; per_[j][h] = 0.f; }

    #pragma unroll
    for (int ct = 0; ct < CT; ++ct) {
        int col = ct * 16 + l15;
        int head = (H == 2) ? (col >> 6) : 0;
        int lc = col & 63;
        float av = al[head * 64 + lc];
        float rv = ar[head * 64 + lc];
        #pragma unroll
        for (int j = 0; j < 4; ++j) {
            float fv = acc[ct][j];
            int gr = brow + row0 + j;
            if (gr < n) feat[(size_t)gr * C + col] = __float2half(fv);
            pel[j][head] += fv * av;
            per_[j][head] += fv * rv;
        }
    }
    #pragma unroll
    for (int off = 1; off < 16; off <<= 1) {
        #pragma unroll
        for (int j = 0; j < 4; ++j)
            #pragma unroll
            for (int h = 0; h < H; ++h) {
                pel[j][h] += __shfl_xor(pel[j][h], off, 64);
                per_[j][h] += __shfl_xor(per_[j][h], off, 64);
            }
    }
    if (l15 == 0) {
        #pragma unroll
        for (int j = 0; j < 4; ++j) {
            int gr = brow + row0 + j;
            if (gr < n) {
                if constexpr (H == 2) {
                    float2 e0 = make_float2(pel[j][0], pel[j][1]);
                    float2 e1 = make_float2(per_[j][0], per_[j][1]);
                    *reinterpret_cast<float2*>(el + (size_t)gr * 2) = e0;
                    *reinterpret_cast<float2*>(er + (size_t)gr * 2) = e1;
                } else {
                    el[gr] = pel[j][0];
                    er[gr] = per_[j][0];
                }
            }
        }
    }
}

// ---------------- fused GAT edge-softmax + aggregate, single-pass, u16 csr ----------------
template <int C, int H>
__launch_bounds__(256)
__global__ void gat_agg(const int* __restrict__ rs, const unsigned short* __restrict__ csr,
                        const float* __restrict__ el, const float* __restrict__ er,
                        const __half* __restrict__ feat, const float* __restrict__ bias,
                        __half* __restrict__ outp, int n)
{
    int node = blockIdx.x * 4 + (threadIdx.x >> 6);
    if (node >= n) return;
    int lane = threadIdx.x & 63;
    int start = rs[node], end = rs[node + 1];

    if constexpr (H == 2) {
        const int slot = lane >> 4;
        const int cl = lane & 15;
        const int h = cl >> 3;
        const float erh = er[(size_t)node * 2 + h];
        float ssum = 0.f;
        float acc[8];
        #pragma unroll
        for (int u = 0; u < 8; ++u) acc[u] = 0.f;
        for (int j = start + slot; j < end; j += 4) {
            int s = csr[j];
            float v = el[(size_t)s * 2 + h] + erh;
            v = v >= 0.f ? v : 0.2f * v;
            float p = __expf(v);
            ssum += p;
            float4 raw = *reinterpret_cast<const float4*>(feat + (size_t)s * C + cl * 8);
            const __half2* hp = reinterpret_cast<const __half2*>(&raw);
            #pragma unroll
            for (int u = 0; u < 4; ++u) {
                float2 f2 = __half22float2(hp[u]);
                acc[2 * u]     = fmaf(p, f2.x, acc[2 * u]);
                acc[2 * u + 1] = fmaf(p, f2.y, acc[2 * u + 1]);
            }
        }
        #pragma unroll
        for (int off = 16; off <= 32; off <<= 1) {
            ssum += __shfl_xor(ssum, off, 64);
            #pragma unroll
            for (int u = 0; u < 8; ++u) acc[u] += __shfl_xor(acc[u], off, 64);
        }
        if (slot == 0) {
            float r = 1.f / fmaxf(ssum, 1e-9f);
            f16x8 o;
            #pragma unroll
            for (int u = 0; u < 8; ++u) o[u] = (_Float16)(acc[u] * r);
            *reinterpret_cast<f16x8*>(outp + (size_t)node * C + cl * 8) = o;
        }
    } else {
        const int slot = lane >> 3;
        const int cl = lane & 7;
        const float er0 = er[node];
        float ssum = 0.f;
        float acc[8];
        #pragma unroll
        for (int u = 0; u < 8; ++u) acc[u] = 0.f;
        for (int j = start + slot; j < end; j += 8) {
            int s = csr[j];
            float v = el[s] + er0;
            v = v >= 0.f ? v : 0.2f * v;
            float p = __expf(v);
            ssum += p;
            float4 raw = *reinterpret_cast<const float4*>(feat + (size_t)s * C + cl * 8);
            const __half2* hp = reinterpret_cast<const __half2*>(&raw);
            #pragma unroll
            for (int u = 0; u < 4; ++u) {
                float2 f2 = __half22float2(hp[u]);
                acc[2 * u]     = fmaf(p, f2.x, acc[2 * u]);
                acc[2 * u + 1] = fmaf(p, f2.y, acc[2 * u + 1]);
            }
        }
        #pragma unroll
        for (int off = 8; off <= 32; off <<= 1) {
            ssum += __shfl_xor(ssum, off, 64);
            #pragma unroll
            for (int u = 0; u < 8; ++u) acc[u] += __shfl_xor(acc[u], off, 64);
        }
        if (slot == 0) {
            float r = 1.f / fmaxf(ssum, 1e-9f);
            f16x8 o;
            #pragma unroll
            for (int u = 0; u < 8; ++u) o[u] = (_Float16)(acc[u] * r + bias[cl * 8 + u]);
            *reinterpret_cast<f16x8*>(outp + (size_t)node * C + cl * 8) = o;
        }
    }
}

// ---------------- BatchNorm stats (C=128), fp16 input ----------------
__global__ void bn_stats(const __half* __restrict__ h, float* __restrict__ sums, int n)
{
    __shared__ float s1[256], s2[256];
    int c = threadIdx.x & 127, half = threadIdx.x >> 7;
    float ls = 0.f, lq = 0.f;
    for (int r = blockIdx.x * 2 + half; r < n; r += gridDim.x * 2) {
        float v = __half2float(h[(size_t)r * 128 + c]);
        ls += v; lq += v * v;
    }
    s1[threadIdx.x] = ls; s2[threadIdx.x] = lq;
    __syncthreads();
    if (threadIdx.x < 128) {
        atomicAdd(&sums[c], s1[threadIdx.x] + s1[threadIdx.x + 128]);
        atomicAdd(&sums[128 + c], s2[threadIdx.x] + s2[threadIdx.x + 128]);
    }
}

// ---------------- predictor: MFMA batched MLP, 64 pairs per block ----------------
__launch_bounds__(256, 5)
__global__ void predictor(const __half* __restrict__ h16,
                          const int* __restrict__ ps, const int* __restrict__ pd,
                          const int* __restrict__ ns, const int* __restrict__ nd,
                          const __half* __restrict__ W1t, const float* __restrict__ b1,
                          const __half* __restrict__ W2t, const float* __restrict__ b2,
                          const float* __restrict__ W3, const float* __restrict__ b3,
                          float* __restrict__ out, int P)
{
    constexpr int AS = 72;
    __shared__ __half zt[64 * AS];
    __shared__ __half w1s[64 * AS];
    __shared__ __half w2s[64 * AS];
    const int tid = threadIdx.x;

    for (int idx = tid; idx < 512; idx += 256) {
        int c = idx >> 3, u = idx & 7;
        *reinterpret_cast<f16x8*>(&w1s[c * AS + u * 8]) =
            *reinterpret_cast<const f16x8*>(W1t + (size_t)c * 64 + u * 8);
        *reinterpret_cast<f16x8*>(&w2s[c * AS + u * 8]) =
            *reinterpret_cast<const f16x8*>(W2t + (size_t)c * 64 + u * 8);
    }

    {
        int p = tid >> 2, q = tid & 3;
        int gp = blockIdx.x * 64 + p;
        int s, d;
        if (gp < P) { s = ps[gp]; d = pd[gp]; }
        else        { s = ns[gp - P]; d = nd[gp - P]; }
        const f16x8* hs = reinterpret_cast<const f16x8*>(h16 + (size_t)s * 64 + q * 16);
        const f16x8* hd = reinterpret_cast<const f16x8*>(h16 + (size_t)d * 64 + q * 16);
        #pragma unroll
        for (int u = 0; u < 2; ++u) {
            f16x8 z = hs[u] * hd[u];
            *reinterpret_cast<f16x8*>(&zt[p * AS + q * 16 + u * 8]) = z;
        }
    }
    __syncthreads();

    const int w = tid >> 6;
    const int l = tid & 63;
    const int l15 = l & 15;
    const int kg = l >> 4;
    const int myrow = (w * 16 + l15) * AS;

    f32x4 acc[4];
    {
        f16x8 a0 = *reinterpret_cast<const f16x8*>(&zt[myrow + kg * 8]);
        f16x8 a1 = *reinterpret_cast<const f16x8*>(&zt[myrow + 32 + kg * 8]);
        #pragma unroll
        for (int nt = 0; nt < 4; ++nt) {
            f16x8 b0 = *reinterpret_cast<const f16x8*>(&w1s[(nt * 16 + l15) * AS + kg * 8]);
            f16x8 b1v = *reinterpret_cast<const f16x8*>(&w1s[(nt * 16 + l15) * AS + 32 + kg * 8]);
            acc[nt] = __builtin_amdgcn_mfma_f32_16x16x32_f16(a0, b0, (f32x4){0.f, 0.f, 0.f, 0.f}, 0, 0, 0);
            acc[nt] = __builtin_amdgcn_mfma_f32_16x16x32_f16(a1, b1v, acc[nt], 0, 0, 0);
        }
    }
    {
        #pragma unroll
        for (int nt = 0; nt < 4; ++nt) {
            float bb = b1[nt * 16 + l15];
            #pragma unroll
            for (int j = 0; j < 4; ++j) {
                float v = fmaxf(acc[nt][j] + bb, 0.f);
                zt[(w * 16 + kg * 4 + j) * AS + nt * 16 + l15] = __float2half(v);
            }
        }
    }
    __syncthreads();

    {
        f16x8 a0 = *reinterpret_cast<const f16x8*>(&zt[myrow + kg * 8]);
        f16x8 a1 = *reinterpret_cast<const f16x8*>(&zt[myrow + 32 + kg * 8]);
        #pragma unroll
        for (int nt = 0; nt < 4; ++nt) {
            f16x8 b0 = *reinterpret_cast<const f16x8*>(&w2s[(nt * 16 + l15) * AS + kg * 8]);
            f16x8 b1v = *reinterpret_cast<const f16x8*>(&w2s[(nt * 16 + l15) * AS + 32 + kg * 8]);
            acc[nt] = __builtin_amdgcn_mfma_f32_16x16x32_f16(a0, b0, (f32x4){0.f, 0.f, 0.f, 0.f}, 0, 0, 0);
            acc[nt] = __builtin_amdgcn_mfma_f32_16x16x32_f16(a1, b1v, acc[nt], 0, 0, 0);
        }
    }
    float part[4] = {0.f, 0.f, 0.f, 0.f};
    #pragma unroll
    for (int nt = 0; nt < 4; ++nt) {
        float bb = b2[nt * 16 + l15];
        float wv = W3[nt * 16 + l15];
        #pragma unroll
        for (int j = 0; j < 4; ++j)
            part[j] += fmaxf(acc[nt][j] + bb, 0.f) * wv;
    }
    #pragma unroll
    for (int off = 1; off < 16; off <<= 1) {
        #pragma unroll
        for (int j = 0; j < 4; ++j)
            part[j] += __shfl_xor(part[j], off, 16);
    }
    if (l15 == 0) {
        const float b3v = b3[0];
        int gp0 = blockIdx.x * 64 + w * 16 + kg * 4;
        #pragma unroll
        for (int j = 0; j < 4; ++j)
            out[gp0 + j] = part[j] + b3v;
    }
}

extern "C" void kernel_launch(void* const* d_in, const int* in_sizes, int n_in,
                              void* d_out, int out_size, void* d_ws, size_t ws_size,
                              hipStream_t stream)
{
    const float* x    = (const float*)d_in[0];
    const int* es     = (const int*)d_in[1];
    const int* ed     = (const int*)d_in[2];
    const int* ps     = (const int*)d_in[3];
    const int* pdst   = (const int*)d_in[4];
    const int* ns     = (const int*)d_in[5];
    const int* nd     = (const int*)d_in[6];
    const float* W0   = (const float*)d_in[7];
    const float* al0  = (const float*)d_in[8];
    const float* ar0  = (const float*)d_in[9];
    const float* W1   = (const float*)d_in[11];
    const float* al1  = (const float*)d_in[12];
    const float* ar1  = (const float*)d_in[13];
    const float* W2   = (const float*)d_in[15];
    const float* al2  = (const float*)d_in[16];
    const float* ar2  = (const float*)d_in[17];
    const float* b2   = (const float*)d_in[18];
    const float* bn0g = (const float*)d_in[19];
    const float* bn0b = (const float*)d_in[20];
    const float* bn1g = (const float*)d_in[21];
    const float* bn1b = (const float*)d_in[22];
    const float* pW1  = (const float*)d_in[23];
    const float* pb1  = (const float*)d_in[24];
    const float* pW2  = (const float*)d_in[25];
    const float* pb2  = (const float*)d_in[26];
    const float* pW3  = (const float*)d_in[27];
    const float* pb3  = (const float*)d_in[28];
    float* out = (float*)d_out;

    float* ws = (float*)d_ws;
    size_t off = 0;
    auto alloc = [&](size_t nelem) {
        float* p = ws + off;
        off += (nelem + 63) & ~(size_t)63;
        return p;
    };
    __half* featb = (__half*)alloc((size_t)N_NODES * 64);   // N x 128 halfs
    __half* xh    = (__half*)alloc((size_t)N_NODES * 64);   // fp16 activations
    __half* aggh  = (__half*)alloc((size_t)N_NODES * 64);   // fp16 aggregate output
    __half* wt0  = (__half*)alloc(128 * 64);
    __half* wt1  = (__half*)alloc(128 * 64);
    __half* wt2  = (__half*)alloc(64 * 64);
    __half* pwt1 = (__half*)alloc(64 * 32);
    __half* pwt2 = (__half*)alloc(64 * 32);
    float* el    = alloc((size_t)N_NODES * 2);
    float* er    = alloc((size_t)N_NODES * 2);
    float* bns   = alloc(512);                               // [0:256)=layer0, [256:512)=layer1
    int* cnt     = (int*)alloc(N_NODES);
    int* rs      = (int*)alloc(N_NODES + 1);
    int* cursor  = (int*)alloc(N_NODES);
    int* bsum    = (int*)alloc(256);
    unsigned short* csr = (unsigned short*)alloc(N_EDGES / 2 + 64);

    dim3 blk(256);
    const int gemmGrid = (N_NODES + 63) / 64;
    const int aggGrid = (N_NODES + 3) / 4;

    // ================= cooperative graph build + prep (1 dispatch) =================
    {
        void* args[] = {
            (void*)&x, (void*)&xh, (void*)&cnt, (void*)&bns,
            (void*)&W0, (void*)&W1, (void*)&W2, (void*)&wt0, (void*)&wt1, (void*)&wt2,
            (void*)&pW1, (void*)&pW2, (void*)&pwt1, (void*)&pwt2,
            (void*)&es, (void*)&ed, (void*)&rs, (void*)&cursor, (void*)&bsum, (void*)&csr
        };
        hipLaunchCooperativeKernel((const void*)build_graph, dim3(1024), blk, args, 0, stream);
    }

    // ================= layer 0 (C=128, H=2) =================
    gemm_mfma<128, 2, false><<<gemmGrid, blk, 0, stream>>>(xh, wt0, al0, ar0,
        nullptr, nullptr, nullptr, featb, el, er, N_NODES);
    gat_agg<128, 2><<<aggGrid, blk, 0, stream>>>(rs, csr, el, er, featb, nullptr, aggh, N_NODES);
    bn_stats<<<256, blk, 0, stream>>>(aggh, bns, N_NODES);

    // ================= layer 1 (C=128, H=2); BN0 fused into gemm =================
    gemm_mfma<128, 2, true><<<gemmGrid, blk, 0, stream>>>(aggh, wt1, al1, ar1,
        bns, bn0g, bn0b, featb, el, er, N_NODES);
    gat_agg<128, 2><<<aggGrid, blk, 0, stream>>>(rs, csr, el, er, featb, nullptr, aggh, N_NODES);
    bn_stats<<<256, blk, 0, stream>>>(aggh, bns + 256, N_NODES);

    // ================= layer 2 (C=64, H=1); BN1 fused into gemm =================
    gemm_mfma<64, 1, true><<<gemmGrid, blk, 0, stream>>>(aggh, wt2, al2, ar2,
        bns + 256, bn1g, bn1b, featb, el, er, N_NODES);
    gat_agg<64, 1><<<aggGrid, blk, 0, stream>>>(rs, csr, el, er, featb, b2, aggh, N_NODES);

    // ================= predictor =================
    predictor<<<3125, blk, 0, stream>>>(aggh, ps, pdst, ns, nd,
                                        pwt1, pb1, pwt2, pb2, pW3, pb3, out, 100000);
}